// Round 2
// baseline (480.444 us; speedup 1.0000x reference)
//
#include <hip/hip_runtime.h>
#include <hip/hip_bf16.h>

#define BB 4
#define HH 160
#define WW 160
#define HWD (HH * WW)                   // 25600
#define OUT_ELEMS (BB * 64 * HWD)       // 6,553,600
#define EPSBN 1e-5f
#define CHSTRIDE (8 * HWD)              // 8-channel chunk stride
#define NSLOT 256                       // BN partial slots per channel-stat

typedef __attribute__((ext_vector_type(8))) short bf16x8;
typedef __attribute__((ext_vector_type(4))) float f32x4;

__device__ inline unsigned pack2bf(float a, float b) {
  __hip_bfloat162 h2 = __float22bfloat162_rn(float2{a, b});
  unsigned u;
  __builtin_memcpy(&u, &h2, 4);
  return u;
}
__device__ inline unsigned short bf16bits(float a) {
  __hip_bfloat16 h = __float2bfloat16(a);
  unsigned short u;
  __builtin_memcpy(&u, &h, 2);
  return u;
}

// XCD-slab tile mapping: blk%8 = XCD (HW round-robin); each XCD owns 200
// spatially-contiguous tiles (an 80-pixel-row band) so halo re-reads stay
// inside one 4MB L2.
__device__ inline void tile_map(int blk, int& b, int& ty0, int& tx0) {
  int t = (blk & 7) * 200 + (blk >> 3);
  b = t / 400;
  int r = t % 400;
  ty0 = (r / 10) * 4;
  tx0 = (r % 10) * 16;
}

// ---------------------------------------------------------------------------
// prep: prepacked MFMA B-fragments (K permuted to kappa = tap*8 + ch within
// each 8-ch chunk, 96-padded; taps 9..11 zero) + zero the BN partial slots.
// ---------------------------------------------------------------------------
__global__ void prep_kernel(const float* __restrict__ cw,
                            const float* __restrict__ ow,
                            unsigned short* __restrict__ Bp,
                            unsigned short* __restrict__ B2p,
                            float* __restrict__ part) {
  int i = blockIdx.x * 256 + threadIdx.x;
  if (i < 32768) part[i] = 0.f;
  if (i < 49152) {                      // dconv weights conv_w[n][c][t], nt 0..3
    int j = i & 7, l = (i >> 3) & 63, rest = i >> 9;
    int ki = rest % 24, nt = rest / 24;
    int kp = ki * 32 + ((l >> 4) << 3) + j;
    int chunk = kp / 96, kq = kp % 96;
    int t = kq >> 3, c = kq & 7;
    int n = nt * 16 + (l & 15);
    float v = (t < 9) ? cw[n * 576 + (chunk * 8 + c) * 9 + t] : 0.f;
    Bp[i] = bf16bits(v);
  }
  if (i < 24576) {                      // offconv weights, nt 0..1, n<18
    int j = i & 7, l = (i >> 3) & 63, rest = i >> 9;
    int ki = rest % 24, nt = rest / 24;
    int kp = ki * 32 + ((l >> 4) << 3) + j;
    int chunk = kp / 96, kq = kp % 96;
    int t = kq >> 3, c = kq & 7;
    int n = nt * 16 + (l & 15);
    float v = (t < 9 && n < 18) ? ow[n * 576 + (chunk * 8 + c) * 9 + t] : 0.f;
    B2p[i] = bf16bits(v);
  }
}

// ---------------------------------------------------------------------------
// FUSED offconv + dconv, M-SPLIT wave mapping.
// Wave wv owns output pixel row py=wv; the interp value a lane computes
// (pixel (wv,li), tap kk*4+lo, 8 ch) IS its own MFMA A-fragment, so A never
// leaves registers -- no Af LDS exchange, ONE barrier per chunk (patch is
// double-buffered). Each wave instead loads all N-block B-fragments per
// chunk (12 coalesced 1KB loads from the 96KB L2-resident weight array),
// issued right after the barrier and hidden under the interp phase.
// LDS = 2*9072 (patch dbuf) + 4608 (offs) = 22752 B.
// ---------------------------------------------------------------------------
__global__ __launch_bounds__(256, 4) void fused_kernel(
    const float* __restrict__ x, const float* __restrict__ d,
    const bf16x8* __restrict__ Bp, const bf16x8* __restrict__ B2p,
    float* __restrict__ out, float* __restrict__ off_out,
    float* __restrict__ part) {
  int b, ty0, tx0;
  tile_map(blockIdx.x, b, ty0, tx0);
  const int tid = threadIdx.x;
  const int wv = tid >> 6, lane = tid & 63;
  const int lo = lane >> 4, li = lane & 15;
  const int px = li, py = wv;
  const int h = ty0 + py, w = tx0 + px;

  __shared__ float patch[2][189 * 12];  // dbuf; phase1 uses first 108*12
  __shared__ float offs_s[64 * 18];     // per-pixel 9 taps x (dy,dx)

  // ---- phase-2 x-staging addresses precomputed ----
  int goffx[6], laddrx[6];
  bool gokx[6];
#pragma unroll
  for (int i = 0; i < 6; ++i) {
    int l = tid + i * 256;
    int c = l / 189, rc = l % 189, r = rc / 21, col = rc % 21;
    int gy = ty0 - 2 + r, gx = tx0 - 2 + col;
    gokx[i] = (l < 1512) && gy >= 0 && gy < HH && gx >= 0 && gx < WW;
    goffx[i] = ((b * 64 + c) * HH + gy) * WW + gx;
    laddrx[i] = rc * 12 + c;
  }

  int cur = 0;

  // ================= phase 1: offconv =================
  f32x4 po0{0.f, 0.f, 0.f, 0.f}, po1{0.f, 0.f, 0.f, 0.f};
  {
    int poff[3];
    bool tre1[3];
#pragma unroll
    for (int kk = 0; kk < 3; ++kk) {
      int t = kk * 4 + lo;
      tre1[kk] = (t < 9);
      poff[kk] = tre1[kk] ? ((py + t / 3) * 18 + px + t % 3) : 0;
    }

    int goff[4], laddr[4];
    bool gok[4];
#pragma unroll
    for (int i = 0; i < 4; ++i) {
      int l = tid + i * 256;
      int c = l / 108, rc = l % 108, r = rc / 18, col = rc % 18;
      int gy = ty0 - 1 + r, gx = tx0 - 1 + col;
      gok[i] = (l < 864) && gy >= 0 && gy < HH && gx >= 0 && gx < WW;
      goff[i] = ((b * 64 + c) * HH + gy) * WW + gx;
      laddr[i] = rc * 12 + c;
    }
    float g[4];
#pragma unroll
    for (int i = 0; i < 4; ++i) g[i] = gok[i] ? d[goff[i]] : 0.f;

    for (int chunk = 0; chunk < 8; ++chunk) {
#pragma unroll
      for (int i = 0; i < 4; ++i) {
        int l = tid + i * 256;
        if (l < 864) patch[cur][laddr[i]] = g[i];
      }
      __syncthreads();
      int nco = ((chunk < 7) ? (chunk + 1) : 7) * CHSTRIDE;
#pragma unroll
      for (int i = 0; i < 4; ++i) g[i] = gok[i] ? d[goff[i] + nco] : 0.f;
      const bf16x8* Bc = B2p + ((chunk * 3) << 6) + lane;
      bf16x8 w00 = Bc[0], w01 = Bc[64], w02 = Bc[128];
      bf16x8 w10 = Bc[1536], w11 = Bc[1600], w12 = Bc[1664];
      union { bf16x8 v; unsigned u[4]; } a[3];
#pragma unroll
      for (int kk = 0; kk < 3; ++kk) {
        if (tre1[kk]) {
          const float* q = patch[cur] + poff[kk] * 12;
          float4 c0 = *(const float4*)(q);
          float4 c1 = *(const float4*)(q + 4);
          a[kk].u[0] = pack2bf(c0.x, c0.y);
          a[kk].u[1] = pack2bf(c0.z, c0.w);
          a[kk].u[2] = pack2bf(c1.x, c1.y);
          a[kk].u[3] = pack2bf(c1.z, c1.w);
        } else {
          a[kk].u[0] = a[kk].u[1] = a[kk].u[2] = a[kk].u[3] = 0u;
        }
      }
      po0 = __builtin_amdgcn_mfma_f32_16x16x32_bf16(a[0].v, w00, po0, 0, 0, 0);
      po0 = __builtin_amdgcn_mfma_f32_16x16x32_bf16(a[1].v, w01, po0, 0, 0, 0);
      po0 = __builtin_amdgcn_mfma_f32_16x16x32_bf16(a[2].v, w02, po0, 0, 0, 0);
      po1 = __builtin_amdgcn_mfma_f32_16x16x32_bf16(a[0].v, w10, po1, 0, 0, 0);
      po1 = __builtin_amdgcn_mfma_f32_16x16x32_bf16(a[1].v, w11, po1, 0, 0, 0);
      po1 = __builtin_amdgcn_mfma_f32_16x16x32_bf16(a[2].v, w12, po1, 0, 0, 0);
      cur ^= 1;
    }
  }

  // issue the first x chunk: HBM latency hides under the phase-1 epilogue
  // + inter-phase barrier + offset unpack
  float gv[6];
#pragma unroll
  for (int i = 0; i < 6; ++i) gv[i] = gokx[i] ? x[goffx[i]] : 0.f;

  {  // phase-1 epilogue: clamp, write global off_out + LDS offs_s
    const int y = ty0 + wv;
#pragma unroll
    for (int nf = 0; nf < 2; ++nf) {
      int n = nf * 16 + li;
      if (n < 18) {
        f32x4 aa = nf ? po1 : po0;
        float4 v;
        v.x = fminf(1.f, fmaxf(-1.f, aa[0]));
        v.y = fminf(1.f, fmaxf(-1.f, aa[1]));
        v.z = fminf(1.f, fmaxf(-1.f, aa[2]));
        v.w = fminf(1.f, fmaxf(-1.f, aa[3]));
        *(float4*)(off_out + ((b * 18 + n) * HH + y) * WW + tx0 + lo * 4) = v;
        int pix = wv * 16 + lo * 4;
        offs_s[(pix + 0) * 18 + n] = v.x;
        offs_s[(pix + 1) * 18 + n] = v.y;
        offs_s[(pix + 2) * 18 + n] = v.z;
        offs_s[(pix + 3) * 18 + n] = v.w;
      }
    }
  }
  __syncthreads();

  // ================= phase 2: dconv =================
  int bs[3];
  float W00[3], W01[3], W10[3], W11[3];
  bool tre[3];
#pragma unroll
  for (int kk = 0; kk < 3; ++kk) {
    int t = kk * 4 + lo;
    tre[kk] = (t < 9);
    if (tre[kk]) {
      float2 dyx = *(const float2*)&offs_s[(wv * 16 + li) * 18 + 2 * t];
      float pyf = (float)(h - 1 + t / 3) + dyx.x;
      float pxf = (float)(w - 1 + t % 3) + dyx.y;
      float y0 = floorf(pyf), x0 = floorf(pxf);
      float wy = pyf - y0, wx = pxf - x0;
      bs[kk] = ((int)y0 - (ty0 - 2)) * 21 + ((int)x0 - (tx0 - 2));
      W00[kk] = (1.f - wy) * (1.f - wx);
      W01[kk] = (1.f - wy) * wx;
      W10[kk] = wy * (1.f - wx);
      W11[kk] = wy * wx;
    } else {
      bs[kk] = 0;
      W00[kk] = W01[kk] = W10[kk] = W11[kk] = 0.f;
    }
  }

  f32x4 acc[4];
#pragma unroll
  for (int i = 0; i < 4; ++i) acc[i] = f32x4{0.f, 0.f, 0.f, 0.f};
  cur = 0;

  for (int chunk = 0; chunk < 8; ++chunk) {
#pragma unroll
    for (int i = 0; i < 6; ++i) {
      int l = tid + i * 256;
      if (l < 1512) patch[cur][laddrx[i]] = gv[i];
    }
    __syncthreads();
    int nco = ((chunk < 7) ? (chunk + 1) : 7) * CHSTRIDE;
#pragma unroll
    for (int i = 0; i < 6; ++i) gv[i] = gokx[i] ? x[goffx[i] + nco] : 0.f;
    // all 12 B-fragments for this chunk: issued here, consumed after interp
    const bf16x8* Bc = Bp + ((chunk * 3) << 6) + lane;
    bf16x8 bwf[4][3];
#pragma unroll
    for (int nf = 0; nf < 4; ++nf)
#pragma unroll
      for (int kk = 0; kk < 3; ++kk)
        bwf[nf][kk] = Bc[(nf * 24 + kk) * 64];
    union { bf16x8 v; unsigned u[4]; } a[3];
#pragma unroll
    for (int kk = 0; kk < 3; ++kk) {
      if (tre[kk]) {
        const float* q = patch[cur] + bs[kk] * 12;
        float4 p00a = *(const float4*)(q);         // corner (0,0) ch0-3
        float4 p00b = *(const float4*)(q + 4);     //            ch4-7
        float4 p01a = *(const float4*)(q + 12);    // corner (0,1)
        float4 p01b = *(const float4*)(q + 16);
        float4 p10a = *(const float4*)(q + 252);   // corner (1,0): +21*12
        float4 p10b = *(const float4*)(q + 256);
        float4 p11a = *(const float4*)(q + 264);   // corner (1,1)
        float4 p11b = *(const float4*)(q + 268);
        float w0 = W00[kk], w1 = W01[kk], w2 = W10[kk], w3 = W11[kk];
        float v0 = fmaf(w3, p11a.x, fmaf(w2, p10a.x, fmaf(w1, p01a.x, w0 * p00a.x)));
        float v1 = fmaf(w3, p11a.y, fmaf(w2, p10a.y, fmaf(w1, p01a.y, w0 * p00a.y)));
        float v2 = fmaf(w3, p11a.z, fmaf(w2, p10a.z, fmaf(w1, p01a.z, w0 * p00a.z)));
        float v3 = fmaf(w3, p11a.w, fmaf(w2, p10a.w, fmaf(w1, p01a.w, w0 * p00a.w)));
        float v4 = fmaf(w3, p11b.x, fmaf(w2, p10b.x, fmaf(w1, p01b.x, w0 * p00b.x)));
        float v5 = fmaf(w3, p11b.y, fmaf(w2, p10b.y, fmaf(w1, p01b.y, w0 * p00b.y)));
        float v6 = fmaf(w3, p11b.z, fmaf(w2, p10b.z, fmaf(w1, p01b.z, w0 * p00b.z)));
        float v7 = fmaf(w3, p11b.w, fmaf(w2, p10b.w, fmaf(w1, p01b.w, w0 * p00b.w)));
        a[kk].u[0] = pack2bf(v0, v1);
        a[kk].u[1] = pack2bf(v2, v3);
        a[kk].u[2] = pack2bf(v4, v5);
        a[kk].u[3] = pack2bf(v6, v7);
      } else {
        a[kk].u[0] = a[kk].u[1] = a[kk].u[2] = a[kk].u[3] = 0u;
      }
    }
#pragma unroll
    for (int nf = 0; nf < 4; ++nf)
#pragma unroll
      for (int kk = 0; kk < 3; ++kk)
        acc[nf] = __builtin_amdgcn_mfma_f32_16x16x32_bf16(
            a[kk].v, bwf[nf][kk], acc[nf], 0, 0, 0);
    cur ^= 1;
  }

  // epilogue: aligned float4 stores + fused BN partial sums.
  // wave wv holds row y=ty0+wv; lane (lo,li): x=tx0+lo*4+r, ch nf*16+li.
  const int y = ty0 + wv;
  float s[4], s2[4];
#pragma unroll
  for (int nf = 0; nf < 4; ++nf) {
    s[nf] = 0.f;
    s2[nf] = 0.f;
    float* pout = out + ((b * 64 + nf * 16 + li) * HH + y) * WW + tx0 + lo * 4;
    *(float4*)pout = make_float4(acc[nf][0], acc[nf][1], acc[nf][2], acc[nf][3]);
#pragma unroll
    for (int r = 0; r < 4; ++r) {
      float v = acc[nf][r];
      s[nf] += v;
      s2[nf] = fmaf(v, v, s2[nf]);
    }
  }
  // reduce across the 4 lanes (lo=0..3) holding the same channel set
#pragma unroll
  for (int nf = 0; nf < 4; ++nf) {
    s[nf] += __shfl_xor(s[nf], 16);
    s[nf] += __shfl_xor(s[nf], 32);
    s2[nf] += __shfl_xor(s2[nf], 16);
    s2[nf] += __shfl_xor(s2[nf], 32);
  }
  if (lo == 0) {
    int slot = blockIdx.x & (NSLOT - 1);
#pragma unroll
    for (int nf = 0; nf < 4; ++nf) {
      atomicAdd(&part[(nf * 16 + li) * NSLOT + slot], s[nf]);
      atomicAdd(&part[(64 + nf * 16 + li) * NSLOT + slot], s2[nf]);
    }
  }
}

// ---------------------------------------------------------------------------
// reduce BN partials: block j sums part[j][0..255] (f64) -> sums[j]
// ---------------------------------------------------------------------------
__global__ __launch_bounds__(256) void reduce_kernel(
    const float* __restrict__ part, double* __restrict__ sums) {
  const int j = blockIdx.x;
  __shared__ double sh[256];
  sh[threadIdx.x] = (double)part[j * NSLOT + threadIdx.x];
  __syncthreads();
  for (int t = 128; t > 0; t >>= 1) {
    if (threadIdx.x < t) sh[threadIdx.x] += sh[threadIdx.x + t];
    __syncthreads();
  }
  if (threadIdx.x == 0) sums[j] = sh[0];
}

// ---------------------------------------------------------------------------
// BN apply + ReLU, in place on d_out's conv region (float4 vectorized).
// ---------------------------------------------------------------------------
__global__ __launch_bounds__(256) void bnapply_kernel(
    float* __restrict__ out, const double* __restrict__ sums,
    const float* __restrict__ gamma, const float* __restrict__ beta) {
  const int i = blockIdx.x * 256 + threadIdx.x;
  if (i >= OUT_ELEMS / 4) return;
  const int o = (i / (HWD / 4)) & 63;
  const float n_inv = 1.0f / (float)(BB * HWD);
  float mean = (float)sums[o] * n_inv;
  float var = (float)sums[64 + o] * n_inv - mean * mean;
  float inv = gamma[o] * rsqrtf(var + EPSBN);
  float bt = beta[o];
  float4 v = ((float4*)out)[i];
  v.x = fmaxf(0.f, (v.x - mean) * inv + bt);
  v.y = fmaxf(0.f, (v.y - mean) * inv + bt);
  v.z = fmaxf(0.f, (v.z - mean) * inv + bt);
  v.w = fmaxf(0.f, (v.w - mean) * inv + bt);
  ((float4*)out)[i] = v;
}

extern "C" void kernel_launch(void* const* d_in, const int* in_sizes, int n_in,
                              void* d_out, int out_size, void* d_ws, size_t ws_size,
                              hipStream_t stream) {
  const float* x = (const float*)d_in[0];
  const float* d = (const float*)d_in[1];
  const float* ow = (const float*)d_in[2];
  const float* cw = (const float*)d_in[3];
  const float* gamma = (const float*)d_in[4];
  const float* beta = (const float*)d_in[5];

  float* out = (float*)d_out;
  float* off_out = out + OUT_ELEMS;

  // ws: sums double[128] | Bp ush[49152] | B2p ush[24576] | part f32[32768]
  double* sums = (double*)d_ws;
  unsigned short* Bp = (unsigned short*)((char*)d_ws + 1024);
  unsigned short* B2p = Bp + 49152;
  float* part = (float*)(B2p + 24576);

  prep_kernel<<<192, 256, 0, stream>>>(cw, ow, Bp, B2p, part);

  fused_kernel<<<1600, 256, 0, stream>>>(x, d, (const bf16x8*)Bp,
                                         (const bf16x8*)B2p, out, off_out,
                                         part);

  reduce_kernel<<<128, 256, 0, stream>>>(part, sums);
  bnapply_kernel<<<(OUT_ELEMS / 4 + 255) / 256, 256, 0, stream>>>(
      out, sums, gamma, beta);
}

// Round 3
// 195.396 us; speedup vs baseline: 2.4588x; 2.4588x over previous
//
#include <hip/hip_runtime.h>
#include <hip/hip_bf16.h>

#define BB 4
#define HH 160
#define WW 160
#define HWD (HH * WW)                   // 25600
#define OUT_ELEMS (BB * 64 * HWD)       // 6,553,600
#define EPSBN 1e-5f
#define CHSTRIDE (8 * HWD)              // 8-channel chunk stride
#define NSLOT 256                       // BN partial slots per channel-stat

typedef __attribute__((ext_vector_type(8))) short bf16x8;
typedef __attribute__((ext_vector_type(4))) float f32x4;

__device__ inline unsigned pack2bf(float a, float b) {
  __hip_bfloat162 h2 = __float22bfloat162_rn(float2{a, b});
  unsigned u;
  __builtin_memcpy(&u, &h2, 4);
  return u;
}
__device__ inline unsigned short bf16bits(float a) {
  __hip_bfloat16 h = __float2bfloat16(a);
  unsigned short u;
  __builtin_memcpy(&u, &h, 2);
  return u;
}

// XCD-slab tile mapping: blk%8 = XCD (HW round-robin); each XCD owns 200
// spatially-contiguous tiles (an 80-pixel-row band) so halo re-reads stay
// inside one 4MB L2.
__device__ inline void tile_map(int blk, int& b, int& ty0, int& tx0) {
  int t = (blk & 7) * 200 + (blk >> 3);
  b = t / 400;
  int r = t % 400;
  ty0 = (r / 10) * 4;
  tx0 = (r % 10) * 16;
}

// ---------------------------------------------------------------------------
// prep: prepacked MFMA B-fragments (K permuted to kappa = tap*8 + ch within
// each 8-ch chunk, 96-padded; taps 9..11 zero) + zero the BN partial slots.
// ---------------------------------------------------------------------------
__global__ void prep_kernel(const float* __restrict__ cw,
                            const float* __restrict__ ow,
                            unsigned short* __restrict__ Bp,
                            unsigned short* __restrict__ B2p,
                            float* __restrict__ part) {
  int i = blockIdx.x * 256 + threadIdx.x;
  if (i < 32768) part[i] = 0.f;
  if (i < 49152) {                      // dconv weights conv_w[n][c][t], nt 0..3
    int j = i & 7, l = (i >> 3) & 63, rest = i >> 9;
    int ki = rest % 24, nt = rest / 24;
    int kp = ki * 32 + ((l >> 4) << 3) + j;
    int chunk = kp / 96, kq = kp % 96;
    int t = kq >> 3, c = kq & 7;
    int n = nt * 16 + (l & 15);
    float v = (t < 9) ? cw[n * 576 + (chunk * 8 + c) * 9 + t] : 0.f;
    Bp[i] = bf16bits(v);
  }
  if (i < 24576) {                      // offconv weights, nt 0..1, n<18
    int j = i & 7, l = (i >> 3) & 63, rest = i >> 9;
    int ki = rest % 24, nt = rest / 24;
    int kp = ki * 32 + ((l >> 4) << 3) + j;
    int chunk = kp / 96, kq = kp % 96;
    int t = kq >> 3, c = kq & 7;
    int n = nt * 16 + (l & 15);
    float v = (t < 9 && n < 18) ? ow[n * 576 + (chunk * 8 + c) * 9 + t] : 0.f;
    B2p[i] = bf16bits(v);
  }
}

// ---------------------------------------------------------------------------
// FUSED offconv + dconv, M-SPLIT wave mapping, register-disciplined.
// Wave wv owns output pixel row py=wv; a lane's interp value (pixel (wv,li),
// tap kk*4+lo, 8 ch) IS its own MFMA A-fragment -- no Af LDS exchange, ONE
// barrier per chunk (patch double-buffered). Inner loop is kk-outer/nf-inner
// so at most 4 B-fragments (16 VGPRs) + 1 A-fragment (4 VGPRs) are live at
// once: round-2's 12-live-B version spilled to scratch (FETCH 29->519MB).
// LDS = 2*9072 (patch dbuf) + 4608 (offs) = 22752 B.
// ---------------------------------------------------------------------------
__global__ __launch_bounds__(256, 4) void fused_kernel(
    const float* __restrict__ x, const float* __restrict__ d,
    const bf16x8* __restrict__ Bp, const bf16x8* __restrict__ B2p,
    float* __restrict__ out, float* __restrict__ off_out,
    float* __restrict__ part) {
  int b, ty0, tx0;
  tile_map(blockIdx.x, b, ty0, tx0);
  const int tid = threadIdx.x;
  const int wv = tid >> 6, lane = tid & 63;
  const int lo = lane >> 4, li = lane & 15;
  const int px = li, py = wv;
  const int h = ty0 + py, w = tx0 + px;

  __shared__ float patch[2][189 * 12];  // dbuf; phase1 uses first 108*12
  __shared__ float offs_s[64 * 18];     // per-pixel 9 taps x (dy,dx)

  // ---- phase-2 x-staging addresses precomputed ----
  int goffx[6], laddrx[6];
  bool gokx[6];
#pragma unroll
  for (int i = 0; i < 6; ++i) {
    int l = tid + i * 256;
    int c = l / 189, rc = l % 189, r = rc / 21, col = rc % 21;
    int gy = ty0 - 2 + r, gx = tx0 - 2 + col;
    gokx[i] = (l < 1512) && gy >= 0 && gy < HH && gx >= 0 && gx < WW;
    goffx[i] = ((b * 64 + c) * HH + gy) * WW + gx;
    laddrx[i] = rc * 12 + c;
  }

  int cur = 0;

  // ================= phase 1: offconv =================
  f32x4 po0{0.f, 0.f, 0.f, 0.f}, po1{0.f, 0.f, 0.f, 0.f};
  {
    int poff[3];
    bool tre1[3];
#pragma unroll
    for (int kk = 0; kk < 3; ++kk) {
      int t = kk * 4 + lo;
      tre1[kk] = (t < 9);
      poff[kk] = tre1[kk] ? ((py + t / 3) * 18 + px + t % 3) : 0;
    }

    int goff[4], laddr[4];
    bool gok[4];
#pragma unroll
    for (int i = 0; i < 4; ++i) {
      int l = tid + i * 256;
      int c = l / 108, rc = l % 108, r = rc / 18, col = rc % 18;
      int gy = ty0 - 1 + r, gx = tx0 - 1 + col;
      gok[i] = (l < 864) && gy >= 0 && gy < HH && gx >= 0 && gx < WW;
      goff[i] = ((b * 64 + c) * HH + gy) * WW + gx;
      laddr[i] = rc * 12 + c;
    }
    float g[4];
#pragma unroll
    for (int i = 0; i < 4; ++i) g[i] = gok[i] ? d[goff[i]] : 0.f;

    for (int chunk = 0; chunk < 8; ++chunk) {
#pragma unroll
      for (int i = 0; i < 4; ++i) {
        int l = tid + i * 256;
        if (l < 864) patch[cur][laddr[i]] = g[i];
      }
      __syncthreads();
      int nco = ((chunk < 7) ? (chunk + 1) : 7) * CHSTRIDE;
#pragma unroll
      for (int i = 0; i < 4; ++i) g[i] = gok[i] ? d[goff[i] + nco] : 0.f;
      const bf16x8* Bc = B2p + ((chunk * 3) << 6) + lane;
#pragma unroll
      for (int kk = 0; kk < 3; ++kk) {
        bf16x8 bw0 = Bc[kk * 64];
        bf16x8 bw1 = Bc[1536 + kk * 64];
        union { bf16x8 v; unsigned u[4]; } a;
        if (tre1[kk]) {
          const float* q = patch[cur] + poff[kk] * 12;
          float4 c0 = *(const float4*)(q);
          float4 c1 = *(const float4*)(q + 4);
          a.u[0] = pack2bf(c0.x, c0.y);
          a.u[1] = pack2bf(c0.z, c0.w);
          a.u[2] = pack2bf(c1.x, c1.y);
          a.u[3] = pack2bf(c1.z, c1.w);
        } else {
          a.u[0] = a.u[1] = a.u[2] = a.u[3] = 0u;
        }
        po0 = __builtin_amdgcn_mfma_f32_16x16x32_bf16(a.v, bw0, po0, 0, 0, 0);
        po1 = __builtin_amdgcn_mfma_f32_16x16x32_bf16(a.v, bw1, po1, 0, 0, 0);
      }
      cur ^= 1;
    }
  }

  // issue the first x chunk: HBM latency hides under the phase-1 epilogue
  // + inter-phase barrier + offset unpack
  float gv[6];
#pragma unroll
  for (int i = 0; i < 6; ++i) gv[i] = gokx[i] ? x[goffx[i]] : 0.f;

  {  // phase-1 epilogue: clamp, write global off_out + LDS offs_s
    const int y = ty0 + wv;
#pragma unroll
    for (int nf = 0; nf < 2; ++nf) {
      int n = nf * 16 + li;
      if (n < 18) {
        f32x4 aa = nf ? po1 : po0;
        float4 v;
        v.x = fminf(1.f, fmaxf(-1.f, aa[0]));
        v.y = fminf(1.f, fmaxf(-1.f, aa[1]));
        v.z = fminf(1.f, fmaxf(-1.f, aa[2]));
        v.w = fminf(1.f, fmaxf(-1.f, aa[3]));
        *(float4*)(off_out + ((b * 18 + n) * HH + y) * WW + tx0 + lo * 4) = v;
        int pix = wv * 16 + lo * 4;
        offs_s[(pix + 0) * 18 + n] = v.x;
        offs_s[(pix + 1) * 18 + n] = v.y;
        offs_s[(pix + 2) * 18 + n] = v.z;
        offs_s[(pix + 3) * 18 + n] = v.w;
      }
    }
  }
  __syncthreads();

  // ================= phase 2: dconv =================
  int bs[3];
  float W00[3], W01[3], W10[3], W11[3];
  bool tre[3];
#pragma unroll
  for (int kk = 0; kk < 3; ++kk) {
    int t = kk * 4 + lo;
    tre[kk] = (t < 9);
    if (tre[kk]) {
      float2 dyx = *(const float2*)&offs_s[(wv * 16 + li) * 18 + 2 * t];
      float pyf = (float)(h - 1 + t / 3) + dyx.x;
      float pxf = (float)(w - 1 + t % 3) + dyx.y;
      float y0 = floorf(pyf), x0 = floorf(pxf);
      float wy = pyf - y0, wx = pxf - x0;
      bs[kk] = ((int)y0 - (ty0 - 2)) * 21 + ((int)x0 - (tx0 - 2));
      W00[kk] = (1.f - wy) * (1.f - wx);
      W01[kk] = (1.f - wy) * wx;
      W10[kk] = wy * (1.f - wx);
      W11[kk] = wy * wx;
    } else {
      bs[kk] = 0;
      W00[kk] = W01[kk] = W10[kk] = W11[kk] = 0.f;
    }
  }

  f32x4 acc[4];
#pragma unroll
  for (int i = 0; i < 4; ++i) acc[i] = f32x4{0.f, 0.f, 0.f, 0.f};
  cur = 0;

  for (int chunk = 0; chunk < 8; ++chunk) {
#pragma unroll
    for (int i = 0; i < 6; ++i) {
      int l = tid + i * 256;
      if (l < 1512) patch[cur][laddrx[i]] = gv[i];
    }
    __syncthreads();
    int nco = ((chunk < 7) ? (chunk + 1) : 7) * CHSTRIDE;
#pragma unroll
    for (int i = 0; i < 6; ++i) gv[i] = gokx[i] ? x[goffx[i] + nco] : 0.f;
    const bf16x8* Bc = Bp + ((chunk * 3) << 6) + lane;
#pragma unroll
    for (int kk = 0; kk < 3; ++kk) {
      // 4 B-fragments for THIS kk only (16 VGPRs live, not 48)
      bf16x8 bw0 = Bc[kk * 64];
      bf16x8 bw1 = Bc[1536 + kk * 64];
      bf16x8 bw2 = Bc[3072 + kk * 64];
      bf16x8 bw3 = Bc[4608 + kk * 64];
      union { bf16x8 v; unsigned u[4]; } a;
      if (tre[kk]) {
        const float* q = patch[cur] + bs[kk] * 12;
        float4 p00a = *(const float4*)(q);         // corner (0,0) ch0-3
        float4 p00b = *(const float4*)(q + 4);     //            ch4-7
        float4 p01a = *(const float4*)(q + 12);    // corner (0,1)
        float4 p01b = *(const float4*)(q + 16);
        float4 p10a = *(const float4*)(q + 252);   // corner (1,0): +21*12
        float4 p10b = *(const float4*)(q + 256);
        float4 p11a = *(const float4*)(q + 264);   // corner (1,1)
        float4 p11b = *(const float4*)(q + 268);
        float w0 = W00[kk], w1 = W01[kk], w2 = W10[kk], w3 = W11[kk];
        float v0 = fmaf(w3, p11a.x, fmaf(w2, p10a.x, fmaf(w1, p01a.x, w0 * p00a.x)));
        float v1 = fmaf(w3, p11a.y, fmaf(w2, p10a.y, fmaf(w1, p01a.y, w0 * p00a.y)));
        float v2 = fmaf(w3, p11a.z, fmaf(w2, p10a.z, fmaf(w1, p01a.z, w0 * p00a.z)));
        float v3 = fmaf(w3, p11a.w, fmaf(w2, p10a.w, fmaf(w1, p01a.w, w0 * p00a.w)));
        float v4 = fmaf(w3, p11b.x, fmaf(w2, p10b.x, fmaf(w1, p01b.x, w0 * p00b.x)));
        float v5 = fmaf(w3, p11b.y, fmaf(w2, p10b.y, fmaf(w1, p01b.y, w0 * p00b.y)));
        float v6 = fmaf(w3, p11b.z, fmaf(w2, p10b.z, fmaf(w1, p01b.z, w0 * p00b.z)));
        float v7 = fmaf(w3, p11b.w, fmaf(w2, p10b.w, fmaf(w1, p01b.w, w0 * p00b.w)));
        a.u[0] = pack2bf(v0, v1);
        a.u[1] = pack2bf(v2, v3);
        a.u[2] = pack2bf(v4, v5);
        a.u[3] = pack2bf(v6, v7);
      } else {
        a.u[0] = a.u[1] = a.u[2] = a.u[3] = 0u;
      }
      acc[0] = __builtin_amdgcn_mfma_f32_16x16x32_bf16(a.v, bw0, acc[0], 0, 0, 0);
      acc[1] = __builtin_amdgcn_mfma_f32_16x16x32_bf16(a.v, bw1, acc[1], 0, 0, 0);
      acc[2] = __builtin_amdgcn_mfma_f32_16x16x32_bf16(a.v, bw2, acc[2], 0, 0, 0);
      acc[3] = __builtin_amdgcn_mfma_f32_16x16x32_bf16(a.v, bw3, acc[3], 0, 0, 0);
    }
    cur ^= 1;
  }

  // epilogue: aligned float4 stores + fused BN partial sums.
  // wave wv holds row y=ty0+wv; lane (lo,li): x=tx0+lo*4+r, ch nf*16+li.
  const int y = ty0 + wv;
  float s[4], s2[4];
#pragma unroll
  for (int nf = 0; nf < 4; ++nf) {
    s[nf] = 0.f;
    s2[nf] = 0.f;
    float* pout = out + ((b * 64 + nf * 16 + li) * HH + y) * WW + tx0 + lo * 4;
    *(float4*)pout = make_float4(acc[nf][0], acc[nf][1], acc[nf][2], acc[nf][3]);
#pragma unroll
    for (int r = 0; r < 4; ++r) {
      float v = acc[nf][r];
      s[nf] += v;
      s2[nf] = fmaf(v, v, s2[nf]);
    }
  }
  // reduce across the 4 lanes (lo=0..3) holding the same channel set
#pragma unroll
  for (int nf = 0; nf < 4; ++nf) {
    s[nf] += __shfl_xor(s[nf], 16);
    s[nf] += __shfl_xor(s[nf], 32);
    s2[nf] += __shfl_xor(s2[nf], 16);
    s2[nf] += __shfl_xor(s2[nf], 32);
  }
  if (lo == 0) {
    int slot = blockIdx.x & (NSLOT - 1);
#pragma unroll
    for (int nf = 0; nf < 4; ++nf) {
      atomicAdd(&part[(nf * 16 + li) * NSLOT + slot], s[nf]);
      atomicAdd(&part[(64 + nf * 16 + li) * NSLOT + slot], s2[nf]);
    }
  }
}

// ---------------------------------------------------------------------------
// reduce BN partials: block j sums part[j][0..255] (f64) -> sums[j]
// ---------------------------------------------------------------------------
__global__ __launch_bounds__(256) void reduce_kernel(
    const float* __restrict__ part, double* __restrict__ sums) {
  const int j = blockIdx.x;
  __shared__ double sh[256];
  sh[threadIdx.x] = (double)part[j * NSLOT + threadIdx.x];
  __syncthreads();
  for (int t = 128; t > 0; t >>= 1) {
    if (threadIdx.x < t) sh[threadIdx.x] += sh[threadIdx.x + t];
    __syncthreads();
  }
  if (threadIdx.x == 0) sums[j] = sh[0];
}

// ---------------------------------------------------------------------------
// BN apply + ReLU, in place on d_out's conv region (float4 vectorized).
// ---------------------------------------------------------------------------
__global__ __launch_bounds__(256) void bnapply_kernel(
    float* __restrict__ out, const double* __restrict__ sums,
    const float* __restrict__ gamma, const float* __restrict__ beta) {
  const int i = blockIdx.x * 256 + threadIdx.x;
  if (i >= OUT_ELEMS / 4) return;
  const int o = (i / (HWD / 4)) & 63;
  const float n_inv = 1.0f / (float)(BB * HWD);
  float mean = (float)sums[o] * n_inv;
  float var = (float)sums[64 + o] * n_inv - mean * mean;
  float inv = gamma[o] * rsqrtf(var + EPSBN);
  float bt = beta[o];
  float4 v = ((float4*)out)[i];
  v.x = fmaxf(0.f, (v.x - mean) * inv + bt);
  v.y = fmaxf(0.f, (v.y - mean) * inv + bt);
  v.z = fmaxf(0.f, (v.z - mean) * inv + bt);
  v.w = fmaxf(0.f, (v.w - mean) * inv + bt);
  ((float4*)out)[i] = v;
}

extern "C" void kernel_launch(void* const* d_in, const int* in_sizes, int n_in,
                              void* d_out, int out_size, void* d_ws, size_t ws_size,
                              hipStream_t stream) {
  const float* x = (const float*)d_in[0];
  const float* d = (const float*)d_in[1];
  const float* ow = (const float*)d_in[2];
  const float* cw = (const float*)d_in[3];
  const float* gamma = (const float*)d_in[4];
  const float* beta = (const float*)d_in[5];

  float* out = (float*)d_out;
  float* off_out = out + OUT_ELEMS;

  // ws: sums double[128] | Bp ush[49152] | B2p ush[24576] | part f32[32768]
  double* sums = (double*)d_ws;
  unsigned short* Bp = (unsigned short*)((char*)d_ws + 1024);
  unsigned short* B2p = Bp + 49152;
  float* part = (float*)(B2p + 24576);

  prep_kernel<<<192, 256, 0, stream>>>(cw, ow, Bp, B2p, part);

  fused_kernel<<<1600, 256, 0, stream>>>(x, d, (const bf16x8*)Bp,
                                         (const bf16x8*)B2p, out, off_out,
                                         part);

  reduce_kernel<<<128, 256, 0, stream>>>(part, sums);
  bnapply_kernel<<<(OUT_ELEMS / 4 + 255) / 256, 256, 0, stream>>>(
      out, sums, gamma, beta);
}

// Round 4
// 187.969 us; speedup vs baseline: 2.5560x; 1.0395x over previous
//
#include <hip/hip_runtime.h>
#include <hip/hip_bf16.h>

#define BB 4
#define HH 160
#define WW 160
#define HWD (HH * WW)                   // 25600
#define OUT_ELEMS (BB * 64 * HWD)       // 6,553,600
#define EPSBN 1e-5f
#define CHSTRIDE (8 * HWD)              // 8-channel chunk stride
#define NSLOT 256                       // BN partial slots per channel-stat

typedef __attribute__((ext_vector_type(8))) short bf16x8;
typedef __attribute__((ext_vector_type(4))) float f32x4;

__device__ inline unsigned pack2bf(float a, float b) {
  __hip_bfloat162 h2 = __float22bfloat162_rn(float2{a, b});
  unsigned u;
  __builtin_memcpy(&u, &h2, 4);
  return u;
}
__device__ inline unsigned short bf16bits(float a) {
  __hip_bfloat16 h = __float2bfloat16(a);
  unsigned short u;
  __builtin_memcpy(&u, &h, 2);
  return u;
}

// XCD-slab tile mapping: blk%8 = XCD (HW round-robin); each XCD owns 200
// spatially-contiguous tiles (an 80-pixel-row band) so halo re-reads stay
// inside one 4MB L2.
__device__ inline void tile_map(int blk, int& b, int& ty0, int& tx0) {
  int t = (blk & 7) * 200 + (blk >> 3);
  b = t / 400;
  int r = t % 400;
  ty0 = (r / 10) * 4;
  tx0 = (r % 10) * 16;
}

// ---------------------------------------------------------------------------
// prep: prepacked MFMA B-fragments (K permuted to kappa = tap*8 + ch within
// each 8-ch chunk, 96-padded; taps 9..11 zero) + zero the BN partial slots.
// ---------------------------------------------------------------------------
__global__ void prep_kernel(const float* __restrict__ cw,
                            const float* __restrict__ ow,
                            unsigned short* __restrict__ Bp,
                            unsigned short* __restrict__ B2p,
                            float* __restrict__ part) {
  int i = blockIdx.x * 256 + threadIdx.x;
  if (i < 32768) part[i] = 0.f;
  if (i < 49152) {                      // dconv weights conv_w[n][c][t], nt 0..3
    int j = i & 7, l = (i >> 3) & 63, rest = i >> 9;
    int ki = rest % 24, nt = rest / 24;
    int kp = ki * 32 + ((l >> 4) << 3) + j;
    int chunk = kp / 96, kq = kp % 96;
    int t = kq >> 3, c = kq & 7;
    int n = nt * 16 + (l & 15);
    float v = (t < 9) ? cw[n * 576 + (chunk * 8 + c) * 9 + t] : 0.f;
    Bp[i] = bf16bits(v);
  }
  if (i < 24576) {                      // offconv weights, nt 0..1, n<18
    int j = i & 7, l = (i >> 3) & 63, rest = i >> 9;
    int ki = rest % 24, nt = rest / 24;
    int kp = ki * 32 + ((l >> 4) << 3) + j;
    int chunk = kp / 96, kq = kp % 96;
    int t = kq >> 3, c = kq & 7;
    int n = nt * 16 + (l & 15);
    float v = (t < 9 && n < 18) ? ow[n * 576 + (chunk * 8 + c) * 9 + t] : 0.f;
    B2p[i] = bf16bits(v);
  }
}

// ---------------------------------------------------------------------------
// FUSED offconv + dconv, M-SPLIT wave mapping, LDS-staged B.
// Wave wv owns output pixel row py=wv; a lane's interp value (pixel (wv,li),
// tap kk*4+lo, 8 ch) IS its own MFMA A-fragment -- no Af LDS exchange, ONE
// barrier per chunk (patch AND B double-buffered). B-fragments for chunk+1
// are loaded cooperatively (12KB, coalesced, L2-resident) into 3 f32x4 regs
// per thread during chunk, written to LDS before the barrier, consumed via
// ds_read_b128 just-in-time per kk: no global latency in the inner loop and
// low register liveness. Round-3's per-kk global B loads + spills (WRITE
// 66MB) are the failure this fixes. launch_bounds (256,3): LDS 47.3KB caps
// at 3 blocks/CU anyway, so the ~170-VGPR budget guarantees no scratch.
// LDS = 2*9072 (patch dbuf) + 4608 (offs) + 2*12288 (B dbuf) = 47328 B.
// ---------------------------------------------------------------------------
__global__ __launch_bounds__(256, 3) void fused_kernel(
    const float* __restrict__ x, const float* __restrict__ d,
    const bf16x8* __restrict__ Bp, const bf16x8* __restrict__ B2p,
    float* __restrict__ out, float* __restrict__ off_out,
    float* __restrict__ part) {
  int b, ty0, tx0;
  tile_map(blockIdx.x, b, ty0, tx0);
  const int tid = threadIdx.x;
  const int wv = tid >> 6, lane = tid & 63;
  const int lo = lane >> 4, li = lane & 15;
  const int px = li, py = wv;
  const int h = ty0 + py, w = tx0 + px;

  __shared__ float patch[2][189 * 12];  // dbuf; phase1 uses first 108*12
  __shared__ float offs_s[64 * 18];     // per-pixel 9 taps x (dy,dx)
  __shared__ f32x4 Bls[2][12 * 64];     // dbuf chunk B-fragments (16B units)

  // ---- phase-2 x-staging addresses precomputed ----
  int goffx[6], laddrx[6];
  bool gokx[6];
#pragma unroll
  for (int i = 0; i < 6; ++i) {
    int l = tid + i * 256;
    int c = l / 189, rc = l % 189, r = rc / 21, col = rc % 21;
    int gy = ty0 - 2 + r, gx = tx0 - 2 + col;
    gokx[i] = (l < 1512) && gy >= 0 && gy < HH && gx >= 0 && gx < WW;
    goffx[i] = ((b * 64 + c) * HH + gy) * WW + gx;
    laddrx[i] = rc * 12 + c;
  }

  int cur = 0;
  const int f0 = wv;  // B-staging fragment group owned by this wave

  // ================= phase 1: offconv =================
  f32x4 po0{0.f, 0.f, 0.f, 0.f}, po1{0.f, 0.f, 0.f, 0.f};
  {
    int poff[3];
    bool tre1[3];
#pragma unroll
    for (int kk = 0; kk < 3; ++kk) {
      int t = kk * 4 + lo;
      tre1[kk] = (t < 9);
      poff[kk] = tre1[kk] ? ((py + t / 3) * 18 + px + t % 3) : 0;
    }

    int goff[4], laddr[4];
    bool gok[4];
#pragma unroll
    for (int i = 0; i < 4; ++i) {
      int l = tid + i * 256;
      int c = l / 108, rc = l % 108, r = rc / 18, col = rc % 18;
      int gy = ty0 - 1 + r, gx = tx0 - 1 + col;
      gok[i] = (l < 864) && gy >= 0 && gy < HH && gx >= 0 && gx < WW;
      goff[i] = ((b * 64 + c) * HH + gy) * WW + gx;
      laddr[i] = rc * 12 + c;
    }
    float g[4];
#pragma unroll
    for (int i = 0; i < 4; ++i) g[i] = gok[i] ? d[goff[i]] : 0.f;

    const f32x4* Bg2 = (const f32x4*)B2p;
    f32x4 bst[3];
    if (tid < 128) {
#pragma unroll
      for (int kk = 0; kk < 3; ++kk)
        bst[kk] = Bg2[((f0 * 24 + kk) << 6) + lane];
    }

    for (int chunk = 0; chunk < 8; ++chunk) {
#pragma unroll
      for (int i = 0; i < 4; ++i) {
        int l = tid + i * 256;
        if (l < 864) patch[cur][laddr[i]] = g[i];
      }
      if (tid < 128) {
#pragma unroll
        for (int kk = 0; kk < 3; ++kk)
          Bls[cur][(f0 * 3 + kk) * 64 + lane] = bst[kk];
      }
      __syncthreads();
      int ncc = (chunk < 7) ? (chunk + 1) : 7;
      int nco = ncc * CHSTRIDE;
#pragma unroll
      for (int i = 0; i < 4; ++i) g[i] = gok[i] ? d[goff[i] + nco] : 0.f;
      if (tid < 128) {
#pragma unroll
        for (int kk = 0; kk < 3; ++kk)
          bst[kk] = Bg2[((f0 * 24 + ncc * 3 + kk) << 6) + lane];
      }
      const bf16x8* Bl = (const bf16x8*)Bls[cur];
#pragma unroll
      for (int kk = 0; kk < 3; ++kk) {
        bf16x8 bw0 = Bl[kk * 64 + lane];
        bf16x8 bw1 = Bl[(3 + kk) * 64 + lane];
        union { bf16x8 v; unsigned u[4]; } a;
        if (tre1[kk]) {
          const float* q = patch[cur] + poff[kk] * 12;
          float4 c0 = *(const float4*)(q);
          float4 c1 = *(const float4*)(q + 4);
          a.u[0] = pack2bf(c0.x, c0.y);
          a.u[1] = pack2bf(c0.z, c0.w);
          a.u[2] = pack2bf(c1.x, c1.y);
          a.u[3] = pack2bf(c1.z, c1.w);
        } else {
          a.u[0] = a.u[1] = a.u[2] = a.u[3] = 0u;
        }
        po0 = __builtin_amdgcn_mfma_f32_16x16x32_bf16(a.v, bw0, po0, 0, 0, 0);
        po1 = __builtin_amdgcn_mfma_f32_16x16x32_bf16(a.v, bw1, po1, 0, 0, 0);
      }
      cur ^= 1;
    }
  }

  // issue the first x chunk + first dconv B chunk: latency hides under the
  // phase-1 epilogue + inter-phase barrier + offset unpack
  float gv[6];
#pragma unroll
  for (int i = 0; i < 6; ++i) gv[i] = gokx[i] ? x[goffx[i]] : 0.f;
  const f32x4* Bg = (const f32x4*)Bp;
  f32x4 bst2[3];
#pragma unroll
  for (int kk = 0; kk < 3; ++kk)
    bst2[kk] = Bg[((f0 * 24 + kk) << 6) + lane];

  {  // phase-1 epilogue: clamp, write global off_out + LDS offs_s
    const int y = ty0 + wv;
#pragma unroll
    for (int nf = 0; nf < 2; ++nf) {
      int n = nf * 16 + li;
      if (n < 18) {
        f32x4 aa = nf ? po1 : po0;
        float4 v;
        v.x = fminf(1.f, fmaxf(-1.f, aa[0]));
        v.y = fminf(1.f, fmaxf(-1.f, aa[1]));
        v.z = fminf(1.f, fmaxf(-1.f, aa[2]));
        v.w = fminf(1.f, fmaxf(-1.f, aa[3]));
        *(float4*)(off_out + ((b * 18 + n) * HH + y) * WW + tx0 + lo * 4) = v;
        int pix = wv * 16 + lo * 4;
        offs_s[(pix + 0) * 18 + n] = v.x;
        offs_s[(pix + 1) * 18 + n] = v.y;
        offs_s[(pix + 2) * 18 + n] = v.z;
        offs_s[(pix + 3) * 18 + n] = v.w;
      }
    }
  }
  __syncthreads();

  // ================= phase 2: dconv =================
  int bs[3];
  float W00[3], W01[3], W10[3], W11[3];
  bool tre[3];
#pragma unroll
  for (int kk = 0; kk < 3; ++kk) {
    int t = kk * 4 + lo;
    tre[kk] = (t < 9);
    if (tre[kk]) {
      float2 dyx = *(const float2*)&offs_s[(wv * 16 + li) * 18 + 2 * t];
      float pyf = (float)(h - 1 + t / 3) + dyx.x;
      float pxf = (float)(w - 1 + t % 3) + dyx.y;
      float y0 = floorf(pyf), x0 = floorf(pxf);
      float wy = pyf - y0, wx = pxf - x0;
      bs[kk] = ((int)y0 - (ty0 - 2)) * 21 + ((int)x0 - (tx0 - 2));
      W00[kk] = (1.f - wy) * (1.f - wx);
      W01[kk] = (1.f - wy) * wx;
      W10[kk] = wy * (1.f - wx);
      W11[kk] = wy * wx;
    } else {
      bs[kk] = 0;
      W00[kk] = W01[kk] = W10[kk] = W11[kk] = 0.f;
    }
  }

  f32x4 acc[4];
#pragma unroll
  for (int i = 0; i < 4; ++i) acc[i] = f32x4{0.f, 0.f, 0.f, 0.f};
  cur = 0;

  for (int chunk = 0; chunk < 8; ++chunk) {
#pragma unroll
    for (int i = 0; i < 6; ++i) {
      int l = tid + i * 256;
      if (l < 1512) patch[cur][laddrx[i]] = gv[i];
    }
#pragma unroll
    for (int kk = 0; kk < 3; ++kk)
      Bls[cur][(f0 * 3 + kk) * 64 + lane] = bst2[kk];
    __syncthreads();
    int ncc = (chunk < 7) ? (chunk + 1) : 7;
    int nco = ncc * CHSTRIDE;
#pragma unroll
    for (int i = 0; i < 6; ++i) gv[i] = gokx[i] ? x[goffx[i] + nco] : 0.f;
#pragma unroll
    for (int kk = 0; kk < 3; ++kk)
      bst2[kk] = Bg[((f0 * 24 + ncc * 3 + kk) << 6) + lane];
    const bf16x8* Bl = (const bf16x8*)Bls[cur];
#pragma unroll
    for (int kk = 0; kk < 3; ++kk) {
      union { bf16x8 v; unsigned u[4]; } a;
      if (tre[kk]) {
        const float* q = patch[cur] + bs[kk] * 12;
        float4 p00a = *(const float4*)(q);         // corner (0,0) ch0-3
        float4 p00b = *(const float4*)(q + 4);     //            ch4-7
        float4 p01a = *(const float4*)(q + 12);    // corner (0,1)
        float4 p01b = *(const float4*)(q + 16);
        float4 p10a = *(const float4*)(q + 252);   // corner (1,0): +21*12
        float4 p10b = *(const float4*)(q + 256);
        float4 p11a = *(const float4*)(q + 264);   // corner (1,1)
        float4 p11b = *(const float4*)(q + 268);
        float w0 = W00[kk], w1 = W01[kk], w2 = W10[kk], w3 = W11[kk];
        float v0 = fmaf(w3, p11a.x, fmaf(w2, p10a.x, fmaf(w1, p01a.x, w0 * p00a.x)));
        float v1 = fmaf(w3, p11a.y, fmaf(w2, p10a.y, fmaf(w1, p01a.y, w0 * p00a.y)));
        float v2 = fmaf(w3, p11a.z, fmaf(w2, p10a.z, fmaf(w1, p01a.z, w0 * p00a.z)));
        float v3 = fmaf(w3, p11a.w, fmaf(w2, p10a.w, fmaf(w1, p01a.w, w0 * p00a.w)));
        float v4 = fmaf(w3, p11b.x, fmaf(w2, p10b.x, fmaf(w1, p01b.x, w0 * p00b.x)));
        float v5 = fmaf(w3, p11b.y, fmaf(w2, p10b.y, fmaf(w1, p01b.y, w0 * p00b.y)));
        float v6 = fmaf(w3, p11b.z, fmaf(w2, p10b.z, fmaf(w1, p01b.z, w0 * p00b.z)));
        float v7 = fmaf(w3, p11b.w, fmaf(w2, p10b.w, fmaf(w1, p01b.w, w0 * p00b.w)));
        a.u[0] = pack2bf(v0, v1);
        a.u[1] = pack2bf(v2, v3);
        a.u[2] = pack2bf(v4, v5);
        a.u[3] = pack2bf(v6, v7);
      } else {
        a.u[0] = a.u[1] = a.u[2] = a.u[3] = 0u;
      }
      bf16x8 bw0 = Bl[kk * 64 + lane];
      bf16x8 bw1 = Bl[(3 + kk) * 64 + lane];
      bf16x8 bw2 = Bl[(6 + kk) * 64 + lane];
      bf16x8 bw3 = Bl[(9 + kk) * 64 + lane];
      acc[0] = __builtin_amdgcn_mfma_f32_16x16x32_bf16(a.v, bw0, acc[0], 0, 0, 0);
      acc[1] = __builtin_amdgcn_mfma_f32_16x16x32_bf16(a.v, bw1, acc[1], 0, 0, 0);
      acc[2] = __builtin_amdgcn_mfma_f32_16x16x32_bf16(a.v, bw2, acc[2], 0, 0, 0);
      acc[3] = __builtin_amdgcn_mfma_f32_16x16x32_bf16(a.v, bw3, acc[3], 0, 0, 0);
    }
    cur ^= 1;
  }

  // epilogue: aligned float4 stores + fused BN partial sums.
  // wave wv holds row y=ty0+wv; lane (lo,li): x=tx0+lo*4+r, ch nf*16+li.
  const int y = ty0 + wv;
  float s[4], s2[4];
#pragma unroll
  for (int nf = 0; nf < 4; ++nf) {
    s[nf] = 0.f;
    s2[nf] = 0.f;
    float* pout = out + ((b * 64 + nf * 16 + li) * HH + y) * WW + tx0 + lo * 4;
    *(float4*)pout = make_float4(acc[nf][0], acc[nf][1], acc[nf][2], acc[nf][3]);
#pragma unroll
    for (int r = 0; r < 4; ++r) {
      float v = acc[nf][r];
      s[nf] += v;
      s2[nf] = fmaf(v, v, s2[nf]);
    }
  }
  // reduce across the 4 lanes (lo=0..3) holding the same channel set
#pragma unroll
  for (int nf = 0; nf < 4; ++nf) {
    s[nf] += __shfl_xor(s[nf], 16);
    s[nf] += __shfl_xor(s[nf], 32);
    s2[nf] += __shfl_xor(s2[nf], 16);
    s2[nf] += __shfl_xor(s2[nf], 32);
  }
  if (lo == 0) {
    int slot = blockIdx.x & (NSLOT - 1);
#pragma unroll
    for (int nf = 0; nf < 4; ++nf) {
      atomicAdd(&part[(nf * 16 + li) * NSLOT + slot], s[nf]);
      atomicAdd(&part[(64 + nf * 16 + li) * NSLOT + slot], s2[nf]);
    }
  }
}

// ---------------------------------------------------------------------------
// reduce BN partials: block j sums part[j][0..255] (f64) -> sums[j]
// ---------------------------------------------------------------------------
__global__ __launch_bounds__(256) void reduce_kernel(
    const float* __restrict__ part, double* __restrict__ sums) {
  const int j = blockIdx.x;
  __shared__ double sh[256];
  sh[threadIdx.x] = (double)part[j * NSLOT + threadIdx.x];
  __syncthreads();
  for (int t = 128; t > 0; t >>= 1) {
    if (threadIdx.x < t) sh[threadIdx.x] += sh[threadIdx.x + t];
    __syncthreads();
  }
  if (threadIdx.x == 0) sums[j] = sh[0];
}

// ---------------------------------------------------------------------------
// BN apply + ReLU, in place on d_out's conv region (float4 vectorized).
// ---------------------------------------------------------------------------
__global__ __launch_bounds__(256) void bnapply_kernel(
    float* __restrict__ out, const double* __restrict__ sums,
    const float* __restrict__ gamma, const float* __restrict__ beta) {
  const int i = blockIdx.x * 256 + threadIdx.x;
  if (i >= OUT_ELEMS / 4) return;
  const int o = (i / (HWD / 4)) & 63;
  const float n_inv = 1.0f / (float)(BB * HWD);
  float mean = (float)sums[o] * n_inv;
  float var = (float)sums[64 + o] * n_inv - mean * mean;
  float inv = gamma[o] * rsqrtf(var + EPSBN);
  float bt = beta[o];
  float4 v = ((float4*)out)[i];
  v.x = fmaxf(0.f, (v.x - mean) * inv + bt);
  v.y = fmaxf(0.f, (v.y - mean) * inv + bt);
  v.z = fmaxf(0.f, (v.z - mean) * inv + bt);
  v.w = fmaxf(0.f, (v.w - mean) * inv + bt);
  ((float4*)out)[i] = v;
}

extern "C" void kernel_launch(void* const* d_in, const int* in_sizes, int n_in,
                              void* d_out, int out_size, void* d_ws, size_t ws_size,
                              hipStream_t stream) {
  const float* x = (const float*)d_in[0];
  const float* d = (const float*)d_in[1];
  const float* ow = (const float*)d_in[2];
  const float* cw = (const float*)d_in[3];
  const float* gamma = (const float*)d_in[4];
  const float* beta = (const float*)d_in[5];

  float* out = (float*)d_out;
  float* off_out = out + OUT_ELEMS;

  // ws: sums double[128] | Bp ush[49152] | B2p ush[24576] | part f32[32768]
  double* sums = (double*)d_ws;
  unsigned short* Bp = (unsigned short*)((char*)d_ws + 1024);
  unsigned short* B2p = Bp + 49152;
  float* part = (float*)(B2p + 24576);

  prep_kernel<<<192, 256, 0, stream>>>(cw, ow, Bp, B2p, part);

  fused_kernel<<<1600, 256, 0, stream>>>(x, d, (const bf16x8*)Bp,
                                         (const bf16x8*)B2p, out, off_out,
                                         part);

  reduce_kernel<<<128, 256, 0, stream>>>(part, sums);
  bnapply_kernel<<<(OUT_ELEMS / 4 + 255) / 256, 256, 0, stream>>>(
      out, sums, gamma, beta);
}